// Round 4
// baseline (436.434 us; speedup 1.0000x reference)
//
#include <hip/hip_runtime.h>
#include <hip/hip_bf16.h>

#define N_NODES 50000
#define N_EDGES 800000
#define D_IN 64
#define D_EDGE 32
#define D_HID 128
#define TILES_TOTAL (N_EDGES / 16)

using u32 = unsigned int;
typedef short bf16x8 __attribute__((ext_vector_type(8)));
typedef float f32x4 __attribute__((ext_vector_type(4)));

// ---- bf16 helpers via bit ops (RNE) ----
__device__ __forceinline__ u32 f2bf(float f) {
    u32 b = __float_as_uint(f);
    return (b + 0x7FFFu + ((b >> 16) & 1u)) >> 16;
}
__device__ __forceinline__ u32 pk2(float lo, float hi) {
    return f2bf(lo) | (f2bf(hi) << 16);
}
__device__ __forceinline__ float bf2f(u32 us) { return __uint_as_float(us << 16); }
__device__ __forceinline__ float tanh_fast(float x) {
    float e = __expf(2.f * x);                       // +inf -> 1, 0 -> -1, NaN-free
    return 1.f - 2.f * __builtin_amdgcn_rcpf(e + 1.f);
}
__device__ __forceinline__ bf16x8 as_frag(uint4 v) { return __builtin_bit_cast(bf16x8, v); }

// ============ one-time weight fragment pack (hidden-unit relabeling) ============
// hidden unit at GEMM2 k-slot (s,q,j) := original W1 column u = 32s+16*(j>>2)+4q+(j&3),
// which is exactly what GEMM1 tile t=2s+(j>>2), lane-group q, reg r=j&3 computes.
__global__ void pack_kernel(const float* __restrict__ W1, const float* __restrict__ W2,
                            uint4* __restrict__ w1p, uint4* __restrict__ w2p) {
    int gid = blockIdx.x * 256 + threadIdx.x;
    if (gid >= 24 * 64) return;
    int frag = gid >> 6, lane = gid & 63;
    int q = (lane >> 4) & 3, c = lane & 15;
    u32 p[4];
    if (frag < 8) {
        int t = frag;
#pragma unroll
        for (int j01 = 0; j01 < 4; ++j01) {
            float lo = W1[(q * 8 + 2 * j01) * D_HID + t * 16 + c];
            float hi = W1[(q * 8 + 2 * j01 + 1) * D_HID + t * 16 + c];
            p[j01] = pk2(lo, hi);
        }
        w1p[t * 64 + lane] = make_uint4(p[0], p[1], p[2], p[3]);
    } else {
        int f = frag - 8, s = f >> 2, t2 = f & 3;
#pragma unroll
        for (int j01 = 0; j01 < 4; ++j01) {
            int j0 = 2 * j01, j1 = j0 + 1;
            int u0 = 32 * s + 16 * (j0 >> 2) + 4 * q + (j0 & 3);
            int u1 = 32 * s + 16 * (j1 >> 2) + 4 * q + (j1 & 3);
            p[j01] = pk2(W2[u0 * D_IN + t2 * 16 + c], W2[u1 * D_IN + t2 * 16 + c]);
        }
        w2p[f * 64 + lane] = make_uint4(p[0], p[1], p[2], p[3]);
    }
}

// ============ edge MLP: transposed MFMA, no LDS transpose ============
__global__ __launch_bounds__(256, 4) void edge_mfma_kernel(
    const float* __restrict__ x, const int* __restrict__ src_idx,
    const int* __restrict__ rank, const float* __restrict__ ea,
    const float* __restrict__ b1, const float* __restrict__ b2,
    const float* __restrict__ av,
    const uint4* __restrict__ w1p, const uint4* __restrict__ w2p,
    u32* __restrict__ msg_s, float* __restrict__ scores_s)
{
    __shared__ uint4 w2lds[1024];                       // 16 KB, shared by 4 waves
    int tid = threadIdx.x;
#pragma unroll
    for (int ph = 0; ph < 4; ++ph) w2lds[tid + ph * 256] = w2p[tid + ph * 256];
    __syncthreads();

    const int wid = tid >> 6, lane = tid & 63, q = lane >> 4, c = lane & 15;

    bf16x8 w1f[8];
#pragma unroll
    for (int t = 0; t < 8; ++t) w1f[t] = as_frag(w1p[t * 64 + lane]);
    f32x4 b2f[4], avf[4];
#pragma unroll
    for (int t2 = 0; t2 < 4; ++t2) {
        float4 tb = *(const float4*)(b2 + t2 * 16 + q * 4);
        float4 ta = *(const float4*)(av + t2 * 16 + q * 4);
        b2f[t2] = f32x4{tb.x, tb.y, tb.z, tb.w};
        avf[t2] = f32x4{ta.x, ta.y, ta.z, ta.w};
    }

    const int nw = gridDim.x * 4;
    for (int T = blockIdx.x * 4 + wid; T < TILES_TOTAL; T += nw) {
        const int eb = T * 16;
        const int rk = rank[eb + c];
        const int sidx = src_idx[eb + c];

        const float4* ar = (const float4*)(ea + (size_t)(eb + c) * D_EDGE + q * 8);
        float4 va = ar[0], vb = ar[1];
        bf16x8 a1 = as_frag(make_uint4(pk2(va.x, va.y), pk2(va.z, va.w),
                                       pk2(vb.x, vb.y), pk2(vb.z, vb.w)));

        bf16x8 bfrag[4];
#pragma unroll
        for (int h2 = 0; h2 < 2; ++h2) {
            f32x4 acc[4];
#pragma unroll
            for (int tt = 0; tt < 4; ++tt) {
                int t = h2 * 4 + tt;
                float4 bb = *(const float4*)(b1 + t * 16 + q * 4);   // row-bias into C
                f32x4 ci = f32x4{bb.x, bb.y, bb.z, bb.w};
                acc[tt] = __builtin_amdgcn_mfma_f32_16x16x32_bf16(w1f[t], a1, ci, 0, 0, 0);
            }
#pragma unroll
            for (int tt = 0; tt < 4; ++tt)
#pragma unroll
                for (int r = 0; r < 4; ++r) acc[tt][r] = tanh_fast(acc[tt][r]);
            bfrag[h2 * 2 + 0] = as_frag(make_uint4(
                pk2(acc[0][0], acc[0][1]), pk2(acc[0][2], acc[0][3]),
                pk2(acc[1][0], acc[1][1]), pk2(acc[1][2], acc[1][3])));
            bfrag[h2 * 2 + 1] = as_frag(make_uint4(
                pk2(acc[2][0], acc[2][1]), pk2(acc[2][2], acc[2][3]),
                pk2(acc[3][0], acc[3][1]), pk2(acc[3][2], acc[3][3])));
        }

        f32x4 acc2[4];
#pragma unroll
        for (int t2 = 0; t2 < 4; ++t2) acc2[t2] = b2f[t2];
#pragma unroll
        for (int s = 0; s < 4; ++s)
#pragma unroll
            for (int t2 = 0; t2 < 4; ++t2) {
                bf16x8 wf = as_frag(w2lds[(s * 4 + t2) * 64 + lane]);
                acc2[t2] = __builtin_amdgcn_mfma_f32_16x16x32_bf16(wf, bfrag[s], acc2[t2], 0, 0, 0);
            }

        // epilogue: lane holds edge c, channels t2*16+q*4+r
        float pr = 0.f;
        u32* mrow = msg_s + (size_t)rk * 32;
#pragma unroll
        for (int t2 = 0; t2 < 4; ++t2) {
            float4 xv = *(const float4*)(x + (size_t)sidx * D_IN + t2 * 16 + q * 4);
            float m0 = xv.x * acc2[t2][0], m1 = xv.y * acc2[t2][1];
            float m2 = xv.z * acc2[t2][2], m3 = xv.w * acc2[t2][3];
            pr = fmaf(m0, avf[t2][0], pr); pr = fmaf(m1, avf[t2][1], pr);
            pr = fmaf(m2, avf[t2][2], pr); pr = fmaf(m3, avf[t2][3], pr);
            uint2 pk; pk.x = pk2(m0, m1); pk.y = pk2(m2, m3);
            *(uint2*)(mrow + t2 * 8 + q * 2) = pk;
        }
        pr += __shfl_xor(pr, 16);
        pr += __shfl_xor(pr, 32);
        if (lane < 16) scores_s[rk] = pr;
    }
}

// ============ sort chain ============
__global__ void zero_kernel(int* __restrict__ p, int n) {
    int i = blockIdx.x * 256 + threadIdx.x;
    if (i < n) p[i] = 0;
}

__global__ void hist_kernel(const int* __restrict__ tgt, int* __restrict__ cnt) {
    int e = blockIdx.x * 256 + threadIdx.x;
    if (e < N_EDGES) atomicAdd(&cnt[tgt[e]], 1);
}

__device__ __forceinline__ int block_incl_scan(int v, int lane, int wid, int* ws) {
    int incl = v;
#pragma unroll
    for (int off = 1; off < 64; off <<= 1) {
        int t = __shfl_up(incl, off);
        if (lane >= off) incl += t;
    }
    if (lane == 63) ws[wid] = incl;
    __syncthreads();
    if (threadIdx.x == 0) {
        int s = 0;
#pragma unroll
        for (int w = 0; w < 4; ++w) { int x = ws[w]; ws[w] = s; s += x; }
    }
    __syncthreads();
    return incl + ws[wid];
}

__global__ __launch_bounds__(256) void scanA_kernel(const int* __restrict__ cnt,
                                                    int* __restrict__ offs,
                                                    int* __restrict__ csum) {
    __shared__ int ws[4];
    int tid = threadIdx.x, lane = tid & 63, wid = tid >> 6;
    int i = blockIdx.x * 256 + tid;
    int v = (i < N_NODES) ? cnt[i] : 0;
    int incl = block_incl_scan(v, lane, wid, ws);
    if (i < N_NODES) offs[i + 1] = incl;
    if (tid == 255) csum[blockIdx.x] = incl;
}

__global__ __launch_bounds__(256) void scanB_kernel(int* __restrict__ csum,
                                                    int* __restrict__ offs, int nchunks) {
    __shared__ int ws[4];
    int tid = threadIdx.x, lane = tid & 63, wid = tid >> 6;
    int v = (tid < nchunks) ? csum[tid] : 0;
    int incl = block_incl_scan(v, lane, wid, ws);
    if (tid < nchunks) csum[tid] = incl - v;   // exclusive base per chunk
    if (tid == 0) offs[0] = 0;
}

__global__ void scanC_kernel(int* __restrict__ offs, const int* __restrict__ csum) {
    int i = blockIdx.x * 256 + threadIdx.x;
    if (i < N_NODES) offs[i + 1] += csum[i >> 8];
}

__global__ void scatter_kernel(const int* __restrict__ tgt, const int* __restrict__ offs,
                               int* __restrict__ cursor, int* __restrict__ sorted,
                               int* __restrict__ rank) {
    int e = blockIdx.x * 256 + threadIdx.x;
    if (e >= N_EDGES) return;
    int t = tgt[e];
    int p = offs[t] + atomicAdd(&cursor[t], 1);
    sorted[p] = e;
    rank[e] = p;
}

// ============ streaming per-node softmax + aggregation ============
__global__ __launch_bounds__(256) void agg_kernel(
    const int* __restrict__ offs, const int* __restrict__ sorted,
    const float* __restrict__ ss, const u32* __restrict__ msg32,
    float* __restrict__ out, float* __restrict__ aw_out)
{
    int node = blockIdx.x * 4 + (threadIdx.x >> 6);
    int lane = threadIdx.x & 63;
    int beg = offs[node], end = offs[node + 1];

    float mx = -3.4e38f;
    for (int k = beg + lane; k < end; k += 64) mx = fmaxf(mx, ss[k]);
#pragma unroll
    for (int off = 32; off; off >>= 1) mx = fmaxf(mx, __shfl_xor(mx, off));

    float den = 0.f;
    for (int k = beg + lane; k < end; k += 64) den += __expf(ss[k] - mx);
#pragma unroll
    for (int off = 32; off; off >>= 1) den += __shfl_xor(den, off);
    float rden = 1.f / den;

    int p = lane >> 5, ch2 = lane & 31;
    float aA = 0.f, aB = 0.f;
    for (int kb = beg; kb < end; kb += 2) {
        int k = kb + p;
        if (k < end) {
            float aw = __expf(ss[k] - mx) * rden;
            u32 m2 = msg32[(size_t)k * 32 + ch2];
            aA = fmaf(bf2f(m2 & 0xffffu), aw, aA);
            aB = fmaf(bf2f(m2 >> 16), aw, aB);
            if (ch2 == 0) aw_out[sorted[k]] = aw;
        }
    }
    aA += __shfl_xor(aA, 32);
    aB += __shfl_xor(aB, 32);
    if (lane < 32) {
        float2 o; o.x = aA; o.y = aB;
        *(float2*)(out + (size_t)node * 64 + lane * 2) = o;
    }
}

// ============ launch ============
extern "C" void kernel_launch(void* const* d_in, const int* in_sizes, int n_in,
                              void* d_out, int out_size, void* d_ws, size_t ws_size,
                              hipStream_t stream)
{
    const float* x  = (const float*)d_in[0];
    const int*   ei = (const int*)d_in[1];
    const float* ea = (const float*)d_in[2];
    const float* W1 = (const float*)d_in[3];
    const float* b1 = (const float*)d_in[4];
    const float* W2 = (const float*)d_in[5];
    const float* b2 = (const float*)d_in[6];
    const float* av = (const float*)d_in[7];
    const int* src = ei;
    const int* tgt = ei + N_EDGES;

    char* ws = (char*)d_ws;
    size_t off = 0;
    u32* msg_s     = (u32*)(ws + off);   off += (size_t)N_EDGES * 32 * 4;  // 102.4 MB
    uint4* w1p     = (uint4*)(ws + off); off += 8 * 64 * 16;
    uint4* w2p     = (uint4*)(ws + off); off += 16 * 64 * 16;
    float* scores_s= (float*)(ws + off); off += (size_t)N_EDGES * 4;
    int* sorted    = (int*)(ws + off);   off += (size_t)N_EDGES * 4;
    int* rank      = (int*)(ws + off);   off += (size_t)N_EDGES * 4;
    int* cnt       = (int*)(ws + off);   off += (size_t)N_NODES * 4;
    int* cursor    = (int*)(ws + off);   off += (size_t)N_NODES * 4;
    int* offs      = (int*)(ws + off);   off += (size_t)(N_NODES + 1) * 4;
    int* csum      = (int*)(ws + off);   off += 256 * 4;

    float* out    = (float*)d_out;
    float* aw_out = out + (size_t)N_NODES * 64;

    const int NCHUNKS = (N_NODES + 255) / 256;   // 196

    pack_kernel<<<6, 256, 0, stream>>>(W1, W2, w1p, w2p);
    zero_kernel<<<(2 * N_NODES + 255) / 256, 256, 0, stream>>>(cnt, 2 * N_NODES);
    hist_kernel<<<(N_EDGES + 255) / 256, 256, 0, stream>>>(tgt, cnt);
    scanA_kernel<<<NCHUNKS, 256, 0, stream>>>(cnt, offs, csum);
    scanB_kernel<<<1, 256, 0, stream>>>(csum, offs, NCHUNKS);
    scanC_kernel<<<NCHUNKS, 256, 0, stream>>>(offs, csum);
    scatter_kernel<<<(N_EDGES + 255) / 256, 256, 0, stream>>>(tgt, offs, cursor, sorted, rank);
    edge_mfma_kernel<<<2048, 256, 0, stream>>>(x, src, rank, ea, b1, b2, av,
                                               w1p, w2p, msg_s, scores_s);
    agg_kernel<<<(N_NODES + 3) / 4, 256, 0, stream>>>(offs, sorted, scores_s, msg_s, out, aw_out);
}

// Round 5
// 419.370 us; speedup vs baseline: 1.0407x; 1.0407x over previous
//
#include <hip/hip_runtime.h>
#include <hip/hip_bf16.h>

#define N_NODES 50000
#define N_EDGES 800000
#define D_IN 64
#define D_EDGE 32
#define D_HID 128
#define TILES_TOTAL (N_EDGES / 16)

using u32 = unsigned int;
typedef short bf16x8 __attribute__((ext_vector_type(8)));
typedef float f32x4 __attribute__((ext_vector_type(4)));

// ---- bf16 helpers via bit ops (RNE) ----
__device__ __forceinline__ u32 f2bf(float f) {
    u32 b = __float_as_uint(f);
    return (b + 0x7FFFu + ((b >> 16) & 1u)) >> 16;
}
__device__ __forceinline__ u32 pk2(float lo, float hi) {
    return f2bf(lo) | (f2bf(hi) << 16);
}
__device__ __forceinline__ float bf2f(u32 us) { return __uint_as_float(us << 16); }
__device__ __forceinline__ float tanh_fast(float x) {
    float e = __expf(2.f * x);                       // +inf -> 1, 0 -> -1, NaN-free
    return 1.f - 2.f * __builtin_amdgcn_rcpf(e + 1.f);
}
__device__ __forceinline__ bf16x8 as_frag(uint4 v) { return __builtin_bit_cast(bf16x8, v); }

// ============ one-time weight fragment pack (hidden-unit relabeling) ============
// hidden unit at GEMM2 k-slot (s,q,j) := original W1 column u = 32s+16*(j>>2)+4q+(j&3),
// which is exactly what GEMM1 tile t=2s+(j>>2), lane-group q, reg r=j&3 computes.
__global__ void pack_kernel(const float* __restrict__ W1, const float* __restrict__ W2,
                            uint4* __restrict__ w1p, uint4* __restrict__ w2p) {
    int gid = blockIdx.x * 256 + threadIdx.x;
    if (gid >= 24 * 64) return;
    int frag = gid >> 6, lane = gid & 63;
    int q = (lane >> 4) & 3, c = lane & 15;
    u32 p[4];
    if (frag < 8) {
        int t = frag;
#pragma unroll
        for (int j01 = 0; j01 < 4; ++j01) {
            float lo = W1[(q * 8 + 2 * j01) * D_HID + t * 16 + c];
            float hi = W1[(q * 8 + 2 * j01 + 1) * D_HID + t * 16 + c];
            p[j01] = pk2(lo, hi);
        }
        w1p[t * 64 + lane] = make_uint4(p[0], p[1], p[2], p[3]);
    } else {
        int f = frag - 8, s = f >> 2, t2 = f & 3;
#pragma unroll
        for (int j01 = 0; j01 < 4; ++j01) {
            int j0 = 2 * j01, j1 = j0 + 1;
            int u0 = 32 * s + 16 * (j0 >> 2) + 4 * q + (j0 & 3);
            int u1 = 32 * s + 16 * (j1 >> 2) + 4 * q + (j1 & 3);
            p[j01] = pk2(W2[u0 * D_IN + t2 * 16 + c], W2[u1 * D_IN + t2 * 16 + c]);
        }
        w2p[f * 64 + lane] = make_uint4(p[0], p[1], p[2], p[3]);
    }
}

// ============ edge MLP: transposed MFMA, edge-ordered coalesced stores ============
__global__ __launch_bounds__(256, 4) void edge_mfma_kernel(
    const float* __restrict__ x, const int* __restrict__ src_idx,
    const float* __restrict__ ea,
    const float* __restrict__ b1, const float* __restrict__ b2,
    const float* __restrict__ av,
    const uint4* __restrict__ w1p, const uint4* __restrict__ w2p,
    u32* __restrict__ msg_s /* [E][32] u32, edge order */,
    float* __restrict__ scores_s /* [E], edge order */)
{
    __shared__ uint4 w2lds[1024];                       // 16 KB, shared by 4 waves
    int tid = threadIdx.x;
#pragma unroll
    for (int ph = 0; ph < 4; ++ph) w2lds[tid + ph * 256] = w2p[tid + ph * 256];
    __syncthreads();

    const int wid = tid >> 6, lane = tid & 63, q = lane >> 4, c = lane & 15;

    bf16x8 w1f[8];
#pragma unroll
    for (int t = 0; t < 8; ++t) w1f[t] = as_frag(w1p[t * 64 + lane]);
    f32x4 b2f[4], avf[4];
#pragma unroll
    for (int t2 = 0; t2 < 4; ++t2) {
        float4 tb = *(const float4*)(b2 + t2 * 16 + q * 4);
        float4 ta = *(const float4*)(av + t2 * 16 + q * 4);
        b2f[t2] = f32x4{tb.x, tb.y, tb.z, tb.w};
        avf[t2] = f32x4{ta.x, ta.y, ta.z, ta.w};
    }

    const int nw = gridDim.x * 4;
    for (int T = blockIdx.x * 4 + wid; T < TILES_TOTAL; T += nw) {
        const int eb = T * 16;
        const int sidx = src_idx[eb + c];

        const float4* ar = (const float4*)(ea + (size_t)(eb + c) * D_EDGE + q * 8);
        float4 va = ar[0], vb = ar[1];
        bf16x8 a1 = as_frag(make_uint4(pk2(va.x, va.y), pk2(va.z, va.w),
                                       pk2(vb.x, vb.y), pk2(vb.z, vb.w)));

        bf16x8 bfrag[4];
#pragma unroll
        for (int h2 = 0; h2 < 2; ++h2) {
            f32x4 acc[4];
#pragma unroll
            for (int tt = 0; tt < 4; ++tt) {
                int t = h2 * 4 + tt;
                float4 bb = *(const float4*)(b1 + t * 16 + q * 4);   // row-bias into C
                f32x4 ci = f32x4{bb.x, bb.y, bb.z, bb.w};
                acc[tt] = __builtin_amdgcn_mfma_f32_16x16x32_bf16(w1f[t], a1, ci, 0, 0, 0);
            }
#pragma unroll
            for (int tt = 0; tt < 4; ++tt)
#pragma unroll
                for (int r = 0; r < 4; ++r) acc[tt][r] = tanh_fast(acc[tt][r]);
            bfrag[h2 * 2 + 0] = as_frag(make_uint4(
                pk2(acc[0][0], acc[0][1]), pk2(acc[0][2], acc[0][3]),
                pk2(acc[1][0], acc[1][1]), pk2(acc[1][2], acc[1][3])));
            bfrag[h2 * 2 + 1] = as_frag(make_uint4(
                pk2(acc[2][0], acc[2][1]), pk2(acc[2][2], acc[2][3]),
                pk2(acc[3][0], acc[3][1]), pk2(acc[3][2], acc[3][3])));
        }

        f32x4 acc2[4];
#pragma unroll
        for (int t2 = 0; t2 < 4; ++t2) acc2[t2] = b2f[t2];
#pragma unroll
        for (int s = 0; s < 4; ++s)
#pragma unroll
            for (int t2 = 0; t2 < 4; ++t2) {
                bf16x8 wf = as_frag(w2lds[(s * 4 + t2) * 64 + lane]);
                acc2[t2] = __builtin_amdgcn_mfma_f32_16x16x32_bf16(wf, bfrag[s], acc2[t2], 0, 0, 0);
            }

        // epilogue: lane holds edge eb+c, channels t2*16+q*4+r; edge-order store
        float pr = 0.f;
        u32* mrow = msg_s + (size_t)(eb + c) * 32;
#pragma unroll
        for (int t2 = 0; t2 < 4; ++t2) {
            float4 xv = *(const float4*)(x + (size_t)sidx * D_IN + t2 * 16 + q * 4);
            float m0 = xv.x * acc2[t2][0], m1 = xv.y * acc2[t2][1];
            float m2 = xv.z * acc2[t2][2], m3 = xv.w * acc2[t2][3];
            pr = fmaf(m0, avf[t2][0], pr); pr = fmaf(m1, avf[t2][1], pr);
            pr = fmaf(m2, avf[t2][2], pr); pr = fmaf(m3, avf[t2][3], pr);
            uint2 pk; pk.x = pk2(m0, m1); pk.y = pk2(m2, m3);
            *(uint2*)(mrow + t2 * 8 + q * 2) = pk;
        }
        pr += __shfl_xor(pr, 16);
        pr += __shfl_xor(pr, 32);
        if (lane < 16) scores_s[eb + lane] = pr;
    }
}

// ============ sort chain ============
__global__ void zero_kernel(int* __restrict__ p, int n) {
    int i = blockIdx.x * 256 + threadIdx.x;
    if (i < n) p[i] = 0;
}

__global__ void hist_kernel(const int* __restrict__ tgt, int* __restrict__ cnt) {
    int e = blockIdx.x * 256 + threadIdx.x;
    if (e < N_EDGES) atomicAdd(&cnt[tgt[e]], 1);
}

__device__ __forceinline__ int block_incl_scan(int v, int lane, int wid, int* ws) {
    int incl = v;
#pragma unroll
    for (int off = 1; off < 64; off <<= 1) {
        int t = __shfl_up(incl, off);
        if (lane >= off) incl += t;
    }
    if (lane == 63) ws[wid] = incl;
    __syncthreads();
    if (threadIdx.x == 0) {
        int s = 0;
#pragma unroll
        for (int w = 0; w < 4; ++w) { int x = ws[w]; ws[w] = s; s += x; }
    }
    __syncthreads();
    return incl + ws[wid];
}

__global__ __launch_bounds__(256) void scanA_kernel(const int* __restrict__ cnt,
                                                    int* __restrict__ offs,
                                                    int* __restrict__ csum) {
    __shared__ int ws[4];
    int tid = threadIdx.x, lane = tid & 63, wid = tid >> 6;
    int i = blockIdx.x * 256 + tid;
    int v = (i < N_NODES) ? cnt[i] : 0;
    int incl = block_incl_scan(v, lane, wid, ws);
    if (i < N_NODES) offs[i + 1] = incl;
    if (tid == 255) csum[blockIdx.x] = incl;
}

__global__ __launch_bounds__(256) void scanB_kernel(int* __restrict__ csum,
                                                    int* __restrict__ offs, int nchunks) {
    __shared__ int ws[4];
    int tid = threadIdx.x, lane = tid & 63, wid = tid >> 6;
    int v = (tid < nchunks) ? csum[tid] : 0;
    int incl = block_incl_scan(v, lane, wid, ws);
    if (tid < nchunks) csum[tid] = incl - v;   // exclusive base per chunk
    if (tid == 0) offs[0] = 0;
}

__global__ void scanC_kernel(int* __restrict__ offs, const int* __restrict__ csum) {
    int i = blockIdx.x * 256 + threadIdx.x;
    if (i < N_NODES) offs[i + 1] += csum[i >> 8];
}

__global__ void scatter_kernel(const int* __restrict__ tgt, const int* __restrict__ offs,
                               int* __restrict__ cursor, int* __restrict__ sorted) {
    int e = blockIdx.x * 256 + threadIdx.x;
    if (e >= N_EDGES) return;
    int t = tgt[e];
    int p = offs[t] + atomicAdd(&cursor[t], 1);
    sorted[p] = e;
}

// ============ per-node softmax + aggregation (gathers edge-ordered data) ============
__global__ __launch_bounds__(256) void agg_kernel(
    const int* __restrict__ offs, const int* __restrict__ sorted,
    const float* __restrict__ ss /* edge order */,
    const u32* __restrict__ msg32 /* edge order */,
    float* __restrict__ out, float* __restrict__ aw_out)
{
    int node = blockIdx.x * 4 + (threadIdx.x >> 6);
    int lane = threadIdx.x & 63;
    int beg = offs[node], end = offs[node + 1];

    float mx = -3.4e38f;
    for (int k = beg + lane; k < end; k += 64) mx = fmaxf(mx, ss[sorted[k]]);
#pragma unroll
    for (int off = 32; off; off >>= 1) mx = fmaxf(mx, __shfl_xor(mx, off));

    float den = 0.f;
    for (int k = beg + lane; k < end; k += 64) den += __expf(ss[sorted[k]] - mx);
#pragma unroll
    for (int off = 32; off; off >>= 1) den += __shfl_xor(den, off);
    float rden = 1.f / den;

    int p = lane >> 5, ch2 = lane & 31;
    float aA = 0.f, aB = 0.f;
    for (int kb = beg; kb < end; kb += 2) {
        int k = kb + p;
        if (k < end) {
            int e = sorted[k];
            float aw = __expf(ss[e] - mx) * rden;
            u32 m2 = msg32[(size_t)e * 32 + ch2];
            aA = fmaf(bf2f(m2 & 0xffffu), aw, aA);
            aB = fmaf(bf2f(m2 >> 16), aw, aB);
            if (ch2 == 0) aw_out[e] = aw;
        }
    }
    aA += __shfl_xor(aA, 32);
    aB += __shfl_xor(aB, 32);
    if (lane < 32) {
        float2 o; o.x = aA; o.y = aB;
        *(float2*)(out + (size_t)node * 64 + lane * 2) = o;
    }
}

// ============ launch ============
extern "C" void kernel_launch(void* const* d_in, const int* in_sizes, int n_in,
                              void* d_out, int out_size, void* d_ws, size_t ws_size,
                              hipStream_t stream)
{
    const float* x  = (const float*)d_in[0];
    const int*   ei = (const int*)d_in[1];
    const float* ea = (const float*)d_in[2];
    const float* W1 = (const float*)d_in[3];
    const float* b1 = (const float*)d_in[4];
    const float* W2 = (const float*)d_in[5];
    const float* b2 = (const float*)d_in[6];
    const float* av = (const float*)d_in[7];
    const int* src = ei;
    const int* tgt = ei + N_EDGES;

    char* ws = (char*)d_ws;
    size_t off = 0;
    u32* msg_s     = (u32*)(ws + off);   off += (size_t)N_EDGES * 32 * 4;  // 102.4 MB
    uint4* w1p     = (uint4*)(ws + off); off += 8 * 64 * 16;
    uint4* w2p     = (uint4*)(ws + off); off += 16 * 64 * 16;
    float* scores_s= (float*)(ws + off); off += (size_t)N_EDGES * 4;
    int* sorted    = (int*)(ws + off);   off += (size_t)N_EDGES * 4;
    int* cnt       = (int*)(ws + off);   off += (size_t)N_NODES * 4;
    int* cursor    = (int*)(ws + off);   off += (size_t)N_NODES * 4;
    int* offs      = (int*)(ws + off);   off += (size_t)(N_NODES + 1) * 4;
    int* csum      = (int*)(ws + off);   off += 256 * 4;

    float* out    = (float*)d_out;
    float* aw_out = out + (size_t)N_NODES * 64;

    const int NCHUNKS = (N_NODES + 255) / 256;   // 196

    pack_kernel<<<6, 256, 0, stream>>>(W1, W2, w1p, w2p);
    zero_kernel<<<(2 * N_NODES + 255) / 256, 256, 0, stream>>>(cnt, 2 * N_NODES);
    hist_kernel<<<(N_EDGES + 255) / 256, 256, 0, stream>>>(tgt, cnt);
    scanA_kernel<<<NCHUNKS, 256, 0, stream>>>(cnt, offs, csum);
    scanB_kernel<<<1, 256, 0, stream>>>(csum, offs, NCHUNKS);
    scanC_kernel<<<NCHUNKS, 256, 0, stream>>>(offs, csum);
    scatter_kernel<<<(N_EDGES + 255) / 256, 256, 0, stream>>>(tgt, offs, cursor, sorted);
    edge_mfma_kernel<<<2048, 256, 0, stream>>>(x, src, ea, b1, b2, av,
                                               w1p, w2p, msg_s, scores_s);
    agg_kernel<<<(N_NODES + 3) / 4, 256, 0, stream>>>(offs, sorted, scores_s, msg_s, out, aw_out);
}

// Round 7
// 379.075 us; speedup vs baseline: 1.1513x; 1.1063x over previous
//
#include <hip/hip_runtime.h>
#include <hip/hip_bf16.h>

#define N_NODES 50000
#define N_EDGES 800000
#define D_IN 64
#define D_EDGE 32
#define D_HID 128
#define TILES_TOTAL (N_EDGES / 16)

using u32 = unsigned int;
typedef short bf16x8 __attribute__((ext_vector_type(8)));
typedef float f32x4 __attribute__((ext_vector_type(4)));

// ---- bf16 helpers via bit ops (RNE) ----
__device__ __forceinline__ u32 f2bf(float f) {
    u32 b = __float_as_uint(f);
    return (b + 0x7FFFu + ((b >> 16) & 1u)) >> 16;
}
__device__ __forceinline__ u32 pk2(float lo, float hi) {
    return f2bf(lo) | (f2bf(hi) << 16);
}
__device__ __forceinline__ float bf2f(u32 us) { return __uint_as_float(us << 16); }
__device__ __forceinline__ float tanh_fast(float x) {
    float e = __expf(2.f * x);                       // +inf -> 1, 0 -> -1, NaN-free
    return 1.f - 2.f * __builtin_amdgcn_rcpf(e + 1.f);
}
__device__ __forceinline__ bf16x8 as_frag(uint4 v) { return __builtin_bit_cast(bf16x8, v); }

// ============ one-time weight fragment pack (hidden-unit relabeling) ============
__global__ void pack_kernel(const float* __restrict__ W1, const float* __restrict__ W2,
                            uint4* __restrict__ w1p, uint4* __restrict__ w2p) {
    int gid = blockIdx.x * 256 + threadIdx.x;
    if (gid >= 24 * 64) return;
    int frag = gid >> 6, lane = gid & 63;
    int q = (lane >> 4) & 3, c = lane & 15;
    u32 p[4];
    if (frag < 8) {
        int t = frag;
#pragma unroll
        for (int j01 = 0; j01 < 4; ++j01) {
            float lo = W1[(q * 8 + 2 * j01) * D_HID + t * 16 + c];
            float hi = W1[(q * 8 + 2 * j01 + 1) * D_HID + t * 16 + c];
            p[j01] = pk2(lo, hi);
        }
        w1p[t * 64 + lane] = make_uint4(p[0], p[1], p[2], p[3]);
    } else {
        int f = frag - 8, s = f >> 2, t2 = f & 3;
#pragma unroll
        for (int j01 = 0; j01 < 4; ++j01) {
            int j0 = 2 * j01, j1 = j0 + 1;
            int u0 = 32 * s + 16 * (j0 >> 2) + 4 * q + (j0 & 3);
            int u1 = 32 * s + 16 * (j1 >> 2) + 4 * q + (j1 & 3);
            p[j01] = pk2(W2[u0 * D_IN + t2 * 16 + c], W2[u1 * D_IN + t2 * 16 + c]);
        }
        w2p[f * 64 + lane] = make_uint4(p[0], p[1], p[2], p[3]);
    }
}

// ============ edge MLP: src-sorted order, LDS-staged coalesced stores ============
__global__ __launch_bounds__(256, 4) void edge_mfma_kernel(
    const float* __restrict__ x,
    const int* __restrict__ srcs /* [E] src node of edge at src-rank p */,
    const int* __restrict__ perm /* [E] edge id at src-rank p */,
    const float* __restrict__ ea,
    const float* __restrict__ b1, const float* __restrict__ b2,
    const float* __restrict__ av,
    const uint4* __restrict__ w1p, const uint4* __restrict__ w2p,
    u32* __restrict__ msg_s /* [E][32] u32, src-rank order */,
    float* __restrict__ scores_s /* [E], src-rank order */)
{
    __shared__ uint4 w2lds[1024];                      // 16 KB
    __shared__ u32 stage[4][512];                      // 2 KB per wave
    int tid = threadIdx.x;
#pragma unroll
    for (int ph = 0; ph < 4; ++ph) w2lds[tid + ph * 256] = w2p[tid + ph * 256];
    __syncthreads();

    const int wid = tid >> 6, lane = tid & 63, q = lane >> 4, c = lane & 15;

    bf16x8 w1f[8];
#pragma unroll
    for (int t = 0; t < 8; ++t) w1f[t] = as_frag(w1p[t * 64 + lane]);
    f32x4 b2f[4], avf[4];
#pragma unroll
    for (int t2 = 0; t2 < 4; ++t2) {
        float4 tb = *(const float4*)(b2 + t2 * 16 + q * 4);
        float4 ta = *(const float4*)(av + t2 * 16 + q * 4);
        b2f[t2] = f32x4{tb.x, tb.y, tb.z, tb.w};
        avf[t2] = f32x4{ta.x, ta.y, ta.z, ta.w};
    }

    const int nw = gridDim.x * 4;
    const int maxIter = (TILES_TOTAL + nw - 1) / nw;

    for (int it = 0; it < maxIter; ++it) {
        const int T = blockIdx.x * 4 + wid + it * nw;
        const bool active = T < TILES_TOTAL;
        const int pb = active ? T * 16 : 0;

        f32x4 acc2[4];
        float pr = 0.f;
        if (active) {
            const int e = perm[pb + c];
            const int sidx = srcs[pb + c];

            const float4* ar = (const float4*)(ea + (size_t)e * D_EDGE + q * 8);
            float4 va = ar[0], vb = ar[1];
            bf16x8 a1 = as_frag(make_uint4(pk2(va.x, va.y), pk2(va.z, va.w),
                                           pk2(vb.x, vb.y), pk2(vb.z, vb.w)));

            bf16x8 bfrag[4];
#pragma unroll
            for (int h2 = 0; h2 < 2; ++h2) {
                f32x4 acc[4];
#pragma unroll
                for (int tt = 0; tt < 4; ++tt) {
                    int t = h2 * 4 + tt;
                    float4 bb = *(const float4*)(b1 + t * 16 + q * 4);
                    f32x4 ci = f32x4{bb.x, bb.y, bb.z, bb.w};
                    acc[tt] = __builtin_amdgcn_mfma_f32_16x16x32_bf16(w1f[t], a1, ci, 0, 0, 0);
                }
#pragma unroll
                for (int tt = 0; tt < 4; ++tt)
#pragma unroll
                    for (int r = 0; r < 4; ++r) acc[tt][r] = tanh_fast(acc[tt][r]);
                bfrag[h2 * 2 + 0] = as_frag(make_uint4(
                    pk2(acc[0][0], acc[0][1]), pk2(acc[0][2], acc[0][3]),
                    pk2(acc[1][0], acc[1][1]), pk2(acc[1][2], acc[1][3])));
                bfrag[h2 * 2 + 1] = as_frag(make_uint4(
                    pk2(acc[2][0], acc[2][1]), pk2(acc[2][2], acc[2][3]),
                    pk2(acc[3][0], acc[3][1]), pk2(acc[3][2], acc[3][3])));
            }

#pragma unroll
            for (int t2 = 0; t2 < 4; ++t2) acc2[t2] = b2f[t2];
#pragma unroll
            for (int s = 0; s < 4; ++s)
#pragma unroll
                for (int t2 = 0; t2 < 4; ++t2) {
                    bf16x8 wf = as_frag(w2lds[(s * 4 + t2) * 64 + lane]);
                    acc2[t2] = __builtin_amdgcn_mfma_f32_16x16x32_bf16(wf, bfrag[s], acc2[t2], 0, 0, 0);
                }

            // messages + score partials (x gather is src-clustered => coalesced)
#pragma unroll
            for (int t2 = 0; t2 < 4; ++t2) {
                float4 xv = *(const float4*)(x + (size_t)sidx * D_IN + t2 * 16 + q * 4);
                acc2[t2][0] *= xv.x; acc2[t2][1] *= xv.y;
                acc2[t2][2] *= xv.z; acc2[t2][3] *= xv.w;
                pr = fmaf(acc2[t2][0], avf[t2][0], pr);
                pr = fmaf(acc2[t2][1], avf[t2][1], pr);
                pr = fmaf(acc2[t2][2], avf[t2][2], pr);
                pr = fmaf(acc2[t2][3], avf[t2][3], pr);
            }
            pr += __shfl_xor(pr, 16);
            pr += __shfl_xor(pr, 32);
        }

        __syncthreads();   // stage region free (prev iter reads done)
        if (active) {
            // channel (t2,q,r) lives at u32 index t2*8 + q*2 + r/2 of edge c's row
            u32* st = stage[wid] + c * 32;
#pragma unroll
            for (int t2 = 0; t2 < 4; ++t2) {
                st[t2 * 8 + q * 2 + 0] = pk2(acc2[t2][0], acc2[t2][1]);
                st[t2 * 8 + q * 2 + 1] = pk2(acc2[t2][2], acc2[t2][3]);
            }
        }
        __syncthreads();   // stage writes visible
        if (active) {
            // lane-contiguous 32B per lane -> fully covered 2KB block
            uint4 v0 = *(uint4*)(stage[wid] + lane * 8);
            uint4 v1 = *(uint4*)(stage[wid] + lane * 8 + 4);
            uint4* gdst = (uint4*)(msg_s + (size_t)pb * 32);
            gdst[lane * 2 + 0] = v0;
            gdst[lane * 2 + 1] = v1;
            if (lane < 16) scores_s[pb + lane] = pr;
        }
    }
}

// ============ sort chain ============
__global__ void zero_kernel(int* __restrict__ p, int n) {
    int i = blockIdx.x * 256 + threadIdx.x;
    if (i < n) p[i] = 0;
}

__global__ void hist2_kernel(const int* __restrict__ src, const int* __restrict__ tgt,
                             int* __restrict__ cnt_s, int* __restrict__ cnt_t) {
    int e = blockIdx.x * 256 + threadIdx.x;
    if (e < N_EDGES) {
        atomicAdd(&cnt_s[src[e]], 1);
        atomicAdd(&cnt_t[tgt[e]], 1);
    }
}

__device__ __forceinline__ int block_incl_scan(int v, int lane, int wid, int* ws) {
    int incl = v;
#pragma unroll
    for (int off = 1; off < 64; off <<= 1) {
        int t = __shfl_up(incl, off);
        if (lane >= off) incl += t;
    }
    if (lane == 63) ws[wid] = incl;
    __syncthreads();
    if (threadIdx.x == 0) {
        int s = 0;
#pragma unroll
        for (int w = 0; w < 4; ++w) { int x = ws[w]; ws[w] = s; s += x; }
    }
    __syncthreads();
    return incl + ws[wid];
}

__global__ __launch_bounds__(256) void scanA_kernel(const int* __restrict__ cnt,
                                                    int* __restrict__ offs,
                                                    int* __restrict__ csum) {
    __shared__ int ws[4];
    int tid = threadIdx.x, lane = tid & 63, wid = tid >> 6;
    int i = blockIdx.x * 256 + tid;
    int v = (i < N_NODES) ? cnt[i] : 0;
    int incl = block_incl_scan(v, lane, wid, ws);
    if (i < N_NODES) offs[i + 1] = incl;
    if (tid == 255) csum[blockIdx.x] = incl;
}

__global__ __launch_bounds__(256) void scanB_kernel(int* __restrict__ csum,
                                                    int* __restrict__ offs, int nchunks) {
    __shared__ int ws[4];
    int tid = threadIdx.x, lane = tid & 63, wid = tid >> 6;
    int v = (tid < nchunks) ? csum[tid] : 0;
    int incl = block_incl_scan(v, lane, wid, ws);
    if (tid < nchunks) csum[tid] = incl - v;   // exclusive base per chunk
    if (tid == 0) offs[0] = 0;
}

__global__ void scanC_kernel(int* __restrict__ offs, const int* __restrict__ csum) {
    int i = blockIdx.x * 256 + threadIdx.x;
    if (i < N_NODES) offs[i + 1] += csum[i >> 8];
}

__global__ void scatter_src_kernel(const int* __restrict__ src, const int* __restrict__ offs_s,
                                   int* __restrict__ cur_s, int* __restrict__ perm,
                                   int* __restrict__ srcs, int* __restrict__ srcrank) {
    int e = blockIdx.x * 256 + threadIdx.x;
    if (e >= N_EDGES) return;
    int s = src[e];
    int p = offs_s[s] + atomicAdd(&cur_s[s], 1);
    perm[p] = e;
    srcs[p] = s;
    srcrank[e] = p;
}

__global__ void scatter_tgt_kernel(const int* __restrict__ tgt, const int* __restrict__ offs_t,
                                   int* __restrict__ cur_t, const int* __restrict__ srcrank,
                                   int* __restrict__ sorted, int* __restrict__ idx2) {
    int e = blockIdx.x * 256 + threadIdx.x;
    if (e >= N_EDGES) return;
    int t = tgt[e];
    int p = offs_t[t] + atomicAdd(&cur_t[t], 1);
    sorted[p] = e;
    idx2[p] = srcrank[e];
}

// ============ per-node softmax + aggregation ============
__global__ __launch_bounds__(256) void agg_kernel(
    const int* __restrict__ offs, const int* __restrict__ sorted,
    const int* __restrict__ idx2,
    const float* __restrict__ ss /* src-rank order */,
    const u32* __restrict__ msg32 /* src-rank order */,
    float* __restrict__ out, float* __restrict__ aw_out)
{
    int node = blockIdx.x * 4 + (threadIdx.x >> 6);
    int lane = threadIdx.x & 63;
    int beg = offs[node], end = offs[node + 1];

    float mx = -3.4e38f;
    for (int k = beg + lane; k < end; k += 64) mx = fmaxf(mx, ss[idx2[k]]);
#pragma unroll
    for (int off = 32; off; off >>= 1) mx = fmaxf(mx, __shfl_xor(mx, off));

    float den = 0.f;
    for (int k = beg + lane; k < end; k += 64) den += __expf(ss[idx2[k]] - mx);
#pragma unroll
    for (int off = 32; off; off >>= 1) den += __shfl_xor(den, off);
    float rden = 1.f / den;

    int p = lane >> 5, ch2 = lane & 31;
    float aA = 0.f, aB = 0.f;
    for (int kb = beg; kb < end; kb += 2) {
        int k = kb + p;
        if (k < end) {
            int r = idx2[k];
            float aw = __expf(ss[r] - mx) * rden;
            u32 m2 = msg32[(size_t)r * 32 + ch2];
            aA = fmaf(bf2f(m2 & 0xffffu), aw, aA);
            aB = fmaf(bf2f(m2 >> 16), aw, aB);
            if (ch2 == 0) aw_out[sorted[k]] = aw;
        }
    }
    aA += __shfl_xor(aA, 32);
    aB += __shfl_xor(aB, 32);
    if (lane < 32) {
        float2 o; o.x = aA; o.y = aB;
        *(float2*)(out + (size_t)node * 64 + lane * 2) = o;
    }
}

// ============ launch ============
extern "C" void kernel_launch(void* const* d_in, const int* in_sizes, int n_in,
                              void* d_out, int out_size, void* d_ws, size_t ws_size,
                              hipStream_t stream)
{
    const float* x  = (const float*)d_in[0];
    const int*   ei = (const int*)d_in[1];
    const float* ea = (const float*)d_in[2];
    const float* W1 = (const float*)d_in[3];
    const float* b1 = (const float*)d_in[4];
    const float* W2 = (const float*)d_in[5];
    const float* b2 = (const float*)d_in[6];
    const float* av = (const float*)d_in[7];
    const int* src = ei;
    const int* tgt = ei + N_EDGES;

    char* ws = (char*)d_ws;
    size_t off = 0;
    u32* msg_s     = (u32*)(ws + off);   off += (size_t)N_EDGES * 32 * 4;  // 102.4 MB
    uint4* w1p     = (uint4*)(ws + off); off += 8 * 64 * 16;
    uint4* w2p     = (uint4*)(ws + off); off += 16 * 64 * 16;
    float* scores_s= (float*)(ws + off); off += (size_t)N_EDGES * 4;
    int* sorted    = (int*)(ws + off);   off += (size_t)N_EDGES * 4;
    int* idx2      = (int*)(ws + off);   off += (size_t)N_EDGES * 4;
    int* perm      = (int*)(ws + off);   off += (size_t)N_EDGES * 4;
    int* srcs      = (int*)(ws + off);   off += (size_t)N_EDGES * 4;
    int* srcrank   = (int*)(ws + off);   off += (size_t)N_EDGES * 4;
    int* cnt4      = (int*)(ws + off);   off += (size_t)4 * N_NODES * 4;
    int* cnt_s = cnt4, *cur_s = cnt4 + N_NODES;
    int* cnt_t = cnt4 + 2 * N_NODES, *cur_t = cnt4 + 3 * N_NODES;
    int* offs_s    = (int*)(ws + off);   off += (size_t)(N_NODES + 1) * 4;
    int* offs_t    = (int*)(ws + off);   off += (size_t)(N_NODES + 1) * 4;
    int* csum      = (int*)(ws + off);   off += 256 * 4;

    float* out    = (float*)d_out;
    float* aw_out = out + (size_t)N_NODES * 64;

    const int NCHUNKS = (N_NODES + 255) / 256;   // 196

    pack_kernel<<<6, 256, 0, stream>>>(W1, W2, w1p, w2p);
    zero_kernel<<<(4 * N_NODES + 255) / 256, 256, 0, stream>>>(cnt4, 4 * N_NODES);
    hist2_kernel<<<(N_EDGES + 255) / 256, 256, 0, stream>>>(src, tgt, cnt_s, cnt_t);
    scanA_kernel<<<NCHUNKS, 256, 0, stream>>>(cnt_s, offs_s, csum);
    scanB_kernel<<<1, 256, 0, stream>>>(csum, offs_s, NCHUNKS);
    scanC_kernel<<<NCHUNKS, 256, 0, stream>>>(offs_s, csum);
    scanA_kernel<<<NCHUNKS, 256, 0, stream>>>(cnt_t, offs_t, csum);
    scanB_kernel<<<1, 256, 0, stream>>>(csum, offs_t, NCHUNKS);
    scanC_kernel<<<NCHUNKS, 256, 0, stream>>>(offs_t, csum);
    scatter_src_kernel<<<(N_EDGES + 255) / 256, 256, 0, stream>>>(src, offs_s, cur_s,
                                                                  perm, srcs, srcrank);
    scatter_tgt_kernel<<<(N_EDGES + 255) / 256, 256, 0, stream>>>(tgt, offs_t, cur_t,
                                                                  srcrank, sorted, idx2);
    edge_mfma_kernel<<<2048, 256, 0, stream>>>(x, srcs, perm, ea, b1, b2, av,
                                               w1p, w2p, msg_s, scores_s);
    agg_kernel<<<(N_NODES + 3) / 4, 256, 0, stream>>>(offs_t, sorted, idx2,
                                                      scores_s, msg_s, out, aw_out);
}